// Round 3
// baseline (299.730 us; speedup 1.0000x reference)
//
#include <hip/hip_runtime.h>

#define NCH   256
#define NPROT 320
#define HW    16384      // 128*128
#define TAU   20.0f
#define EPSN  1e-4f

// ---------------------------------------------------------------------------
// Kernel 1a: avg-pool sup_x (5,256,128,128) over 16x16 cells -> praw[p][c]
// One block per (s,c) plane. Fully coalesced float4 reads; no atomics.
// ---------------------------------------------------------------------------
__global__ __launch_bounds__(256) void k_pool(const float* __restrict__ sup_x,
                                              float* __restrict__ praw) {
    int b = blockIdx.x;            // s*256 + c
    int t = threadIdx.x;
    const float4* plane = (const float4*)(sup_x + (size_t)b * HW);
    float rsum[8];
    #pragma unroll
    for (int r = 0; r < 8; ++r) rsum[r] = 0.f;
    #pragma unroll
    for (int i = 0; i < 16; ++i) {
        float4 v = plane[i * 256 + t];          // h = i*8 + (t>>5), w4 = t&31
        rsum[i >> 1] += v.x + v.y + v.z + v.w;  // cell row R = h>>4 = i>>1
    }
    __shared__ float part[8][256];
    #pragma unroll
    for (int r = 0; r < 8; ++r) part[r][t] = rsum[r];
    __syncthreads();
    int R  = t >> 5;
    int cw = t & 31;               // = C*4 + bsub
    float s = 0.f;
    #pragma unroll
    for (int a = 0; a < 8; ++a) s += part[R][a * 32 + cw];
    s += __shfl_xor(s, 1);
    s += __shfl_xor(s, 2);
    if ((t & 3) == 0) {
        int shot = b >> 8, c = b & 255;
        int p = shot * 64 + R * 8 + (cw >> 2);
        praw[(size_t)p * NCH + c] = s * (1.0f / 256.0f);
    }
}

// ---------------------------------------------------------------------------
// Kernel 1b: per-proto center + safe-normalize; PT transposed (float4 per
// 4-channel block, proto-major within block); sp[p] = sum_c pro_n[p][c].
// ---------------------------------------------------------------------------
__device__ __forceinline__ float block_sum256(float x, float* ws4, int t) {
    #pragma unroll
    for (int o = 1; o < 64; o <<= 1) x += __shfl_xor(x, o);
    if ((t & 63) == 0) ws4[t >> 6] = x;
    __syncthreads();
    float r = ws4[0] + ws4[1] + ws4[2] + ws4[3];
    __syncthreads();
    return r;
}

__global__ __launch_bounds__(256) void k_norm(const float* __restrict__ praw,
                                              float* __restrict__ PT,
                                              float* __restrict__ sp) {
    int p = blockIdx.x;
    int c = threadIdx.x;
    __shared__ float ws4[4];
    float v = praw[p * NCH + c];
    float mean = block_sum256(v, ws4, c) * (1.0f / 256.0f);
    float cen = v - mean;
    float n2 = block_sum256(cen * cen, ws4, c);
    float inv = 1.0f / fmaxf(sqrtf(n2), EPSN);
    float pn = cen * inv;
    PT[(size_t)(c >> 2) * NPROT * 4 + p * 4 + (c & 3)] = pn;
    float ssum = block_sum256(pn, ws4, c);
    if (c == 0) sp[p] = ssum;
}

// ---------------------------------------------------------------------------
// Kernel 2: fused normalize(qry) -> 320 dots -> softmax-weighted mean + argmax
// 16 pixels/block, 256 threads = 4 waves -> grid 1024 = 4 blocks/CU
// (4 waves/SIMD). Wave w owns pixels w*4..w*4+3; lane l owns protos
// {l + 64j, j=0..4}. Software-pipelined: PT float4s and q float4s for cb+1
// are prefetched into a second register buffer during the cb FMA burst.
// ---------------------------------------------------------------------------
__global__ __launch_bounds__(256, 4) void k_main(const float* __restrict__ qry,
                                                 const float* __restrict__ PT,
                                                 const float* __restrict__ sp,
                                                 float* __restrict__ out) {
    // smem layout (floats):
    //  [0, 4160)      qlds 16 x 260  (later reused: M/S/T/I 4 x (16 x 65))
    //  [4160, 4416)   norm partial s1   (later reused: P2m/s/t/i 4 x 144)
    //  [4416, 4672)   norm partial s2
    //  [4736, 4752)   meanv ; [4752, 4768) invnv
    __shared__ __align__(16) float smem[4768];
    int t = threadIdx.x;
    int pixbase = blockIdx.x * 16;

    // ---- stage 16 pixels x 256 channels ----
    {
        int f4 = t & 3;            // float4-of-pixels (0..3)
        int c0 = t >> 2;           // 0..63
        #pragma unroll
        for (int i = 0; i < 4; ++i) {
            int c = c0 + 64 * i;
            float4 v = *(const float4*)(qry + (size_t)c * HW + pixbase + f4 * 4);
            int px = f4 * 4;
            smem[(px + 0) * 260 + c] = v.x;
            smem[(px + 1) * 260 + c] = v.y;
            smem[(px + 2) * 260 + c] = v.z;
            smem[(px + 3) * 260 + c] = v.w;
        }
    }
    __syncthreads();

    // ---- per-pixel mean and inverse safe-norm ----
    {
        int pix = t & 15, sub = t >> 4;     // 16 subs x 16 channels
        float s1 = 0.f, s2 = 0.f;
        #pragma unroll
        for (int j = 0; j < 16; ++j) {
            float q = smem[pix * 260 + sub * 16 + j];
            s1 += q; s2 += q * q;
        }
        smem[4160 + sub * 16 + pix] = s1;
        smem[4416 + sub * 16 + pix] = s2;
    }
    __syncthreads();
    if (t < 16) {
        float s1 = 0.f, s2 = 0.f;
        #pragma unroll
        for (int j = 0; j < 16; ++j) { s1 += smem[4160 + j * 16 + t]; s2 += smem[4416 + j * 16 + t]; }
        float mean = s1 * (1.0f / 256.0f);
        float n2 = fmaxf(s2 - s1 * mean, 0.f);
        smem[4736 + t] = mean;
        smem[4752 + t] = 1.0f / fmaxf(sqrtf(n2), EPSN);
    }
    __syncthreads();

    // ---- software-pipelined dot products: 4 pixels x 5 protos per thread ----
    int lane = t & 63;
    int w = t >> 6;
    float acc[4][5];
    #pragma unroll
    for (int i = 0; i < 4; ++i)
        #pragma unroll
        for (int j = 0; j < 5; ++j) acc[i][j] = 0.f;

    const float4* P4 = (const float4*)PT + lane;
    const float* qrow = smem + w * 4 * 260;

    float4 pa[5], pb[5], qa[4], qn[4];
    #pragma unroll
    for (int j = 0; j < 5; ++j) pa[j] = P4[j * 64];
    #pragma unroll
    for (int i = 0; i < 4; ++i) qa[i] = *(const float4*)(qrow + i * 260);

#define FMA_BURST(QV, PV)                                              \
    do {                                                               \
        _Pragma("unroll")                                              \
        for (int i = 0; i < 4; ++i) {                                  \
            float4 qv = QV[i];                                         \
            _Pragma("unroll")                                          \
            for (int j = 0; j < 5; ++j) {                              \
                acc[i][j] = fmaf(qv.x, PV[j].x, acc[i][j]);            \
                acc[i][j] = fmaf(qv.y, PV[j].y, acc[i][j]);            \
                acc[i][j] = fmaf(qv.z, PV[j].z, acc[i][j]);            \
                acc[i][j] = fmaf(qv.w, PV[j].w, acc[i][j]);            \
            }                                                          \
        }                                                              \
    } while (0)

    for (int cb = 0; cb < 64; cb += 2) {
        // prefetch cb+1 (cb+1 <= 63 always)
        {
            const float4* Pn = P4 + (size_t)(cb + 1) * NPROT;
            #pragma unroll
            for (int j = 0; j < 5; ++j) pb[j] = Pn[j * 64];
            #pragma unroll
            for (int i = 0; i < 4; ++i) qn[i] = *(const float4*)(qrow + i * 260 + (cb + 1) * 4);
        }
        FMA_BURST(qa, pa);
        // prefetch cb+2 (clamped; q read at cb=64 lands in the 260-pad, unused)
        {
            int cb2 = (cb + 2 < 64) ? (cb + 2) : 63;
            const float4* Pm = P4 + (size_t)cb2 * NPROT;
            #pragma unroll
            for (int j = 0; j < 5; ++j) pa[j] = Pm[j * 64];
            #pragma unroll
            for (int i = 0; i < 4; ++i) qa[i] = *(const float4*)(qrow + i * 260 + (cb + 2) * 4);
        }
        FMA_BURST(qn, pb);
    }
#undef FMA_BURST

    // ---- per-thread softmax partials over 5 protos, per pixel ----
    float spv[5];
    #pragma unroll
    for (int j = 0; j < 5; ++j) spv[j] = sp[lane + 64 * j];

    float m4[4], S4[4], T4[4], I4[4];
    #pragma unroll
    for (int i = 0; i < 4; ++i) {
        int pix = w * 4 + i;
        float mean = smem[4736 + pix], invn = smem[4752 + pix];
        float d[5];
        float m = -1e30f; int bj = 0;
        #pragma unroll
        for (int j = 0; j < 5; ++j) {
            d[j] = TAU * invn * (acc[i][j] - mean * spv[j]);
            if (d[j] > m) { m = d[j]; bj = j; }
        }
        float S = 0.f, T = 0.f;
        #pragma unroll
        for (int j = 0; j < 5; ++j) {
            float e = __expf(d[j] - m);
            S += e; T += e * d[j];
        }
        m4[i] = m; S4[i] = S; T4[i] = T; I4[i] = (float)(lane + 64 * bj);
    }
    __syncthreads();   // all waves done reading qlds; safe to alias

    float* M  = smem;
    float* Sa = smem + 1040;
    float* Ta = smem + 2080;
    float* Ia = smem + 3120;
    #pragma unroll
    for (int i = 0; i < 4; ++i) {
        int pix = w * 4 + i;
        M [pix * 65 + lane] = m4[i];
        Sa[pix * 65 + lane] = S4[i];
        Ta[pix * 65 + lane] = T4[i];
        Ia[pix * 65 + lane] = I4[i];
    }
    __syncthreads();

    // ---- stage 2: merge 8 lanes per (pixel, octant) ----
    float* P2m = smem + 4160;
    float* P2s = smem + 4304;
    float* P2t = smem + 4448;
    float* P2i = smem + 4592;
    if (t < 128) {
        int pix = t >> 3, oct = t & 7;
        int base = pix * 65 + oct * 8;
        float gm = -1e30f;
        #pragma unroll
        for (int k = 0; k < 8; ++k) gm = fmaxf(gm, M[base + k]);
        float S = 0.f, T = 0.f, bi = 0.f, bm = -1e30f;
        #pragma unroll
        for (int k = 0; k < 8; ++k) {
            float mk = M[base + k];
            float wg = __expf(mk - gm);
            S += Sa[base + k] * wg;
            T += Ta[base + k] * wg;
            if (mk > bm) { bm = mk; bi = Ia[base + k]; }
        }
        P2m[pix * 9 + oct] = gm;
        P2s[pix * 9 + oct] = S;
        P2t[pix * 9 + oct] = T;
        P2i[pix * 9 + oct] = bi;
    }
    __syncthreads();

    // ---- stage 3: merge 8 octants, write out ----
    if (t < 16) {
        float gm = -1e30f;
        #pragma unroll
        for (int k = 0; k < 8; ++k) gm = fmaxf(gm, P2m[t * 9 + k]);
        float S = 0.f, T = 0.f, bi = 0.f, bm = -1e30f;
        #pragma unroll
        for (int k = 0; k < 8; ++k) {
            float mk = P2m[t * 9 + k];
            float wg = __expf(mk - gm);
            S += P2s[t * 9 + k] * wg;
            T += P2t[t * 9 + k] * wg;
            if (mk > bm) { bm = mk; bi = P2i[t * 9 + k]; }
        }
        out[pixbase + t] = T / S;           // pred_grid
        out[HW + pixbase + t] = bi;         // debug_assign
    }
}

extern "C" void kernel_launch(void* const* d_in, const int* in_sizes, int n_in,
                              void* d_out, int out_size, void* d_ws, size_t ws_size,
                              hipStream_t stream) {
    const float* qry   = (const float*)d_in[0];   // (1,1,256,128,128)
    const float* sup_x = (const float*)d_in[1];   // (1,5,1,256,128,128)
    float* out = (float*)d_out;                   // 16384 pred + 16384 assign

    float* praw = (float*)d_ws;                          // 320*256 fp32
    float* PT   = praw + NPROT * NCH;                    // 320*256 fp32 (transposed)
    float* sp   = PT + NPROT * NCH;                      // 320 fp32

    k_pool<<<5 * 256, 256, 0, stream>>>(sup_x, praw);
    k_norm<<<NPROT, 256, 0, stream>>>(praw, PT, sp);
    k_main<<<HW / 16, 256, 0, stream>>>(qry, PT, sp, out);
}

// Round 4
// 252.709 us; speedup vs baseline: 1.1861x; 1.1861x over previous
//
#include <hip/hip_runtime.h>

#define NCH   256
#define NPROT 320
#define HW    16384      // 128*128
#define TAU   20.0f
#define EPSN  1e-4f
#define NGRP  16         // proto groups
#define PPG   20         // protos per group

// ---------------------------------------------------------------------------
// Kernel 1a: avg-pool sup_x (5,256,128,128) over 16x16 cells -> praw[p][c]
// One block per (s,c) plane. Fully coalesced float4 reads; no atomics.
// ---------------------------------------------------------------------------
__global__ __launch_bounds__(256) void k_pool(const float* __restrict__ sup_x,
                                              float* __restrict__ praw) {
    int b = blockIdx.x;            // s*256 + c
    int t = threadIdx.x;
    const float4* plane = (const float4*)(sup_x + (size_t)b * HW);
    float rsum[8];
    #pragma unroll
    for (int r = 0; r < 8; ++r) rsum[r] = 0.f;
    #pragma unroll
    for (int i = 0; i < 16; ++i) {
        float4 v = plane[i * 256 + t];          // h = i*8 + (t>>5), w4 = t&31
        rsum[i >> 1] += v.x + v.y + v.z + v.w;  // cell row R = h>>4 = i>>1
    }
    __shared__ float part[8][256];
    #pragma unroll
    for (int r = 0; r < 8; ++r) part[r][t] = rsum[r];
    __syncthreads();
    int R  = t >> 5;
    int cw = t & 31;               // = C*4 + bsub
    float s = 0.f;
    #pragma unroll
    for (int a = 0; a < 8; ++a) s += part[R][a * 32 + cw];
    s += __shfl_xor(s, 1);
    s += __shfl_xor(s, 2);
    if ((t & 3) == 0) {
        int shot = b >> 8, c = b & 255;
        int p = shot * 64 + R * 8 + (cw >> 2);
        praw[(size_t)p * NCH + c] = s * (1.0f / 256.0f);
    }
}

// ---------------------------------------------------------------------------
// Kernel 1b: per-proto center + safe-normalize IN PLACE (row-major, block p
// owns row p so read/write same row is safe); sp[p] = sum_c pro_n[p][c].
// ---------------------------------------------------------------------------
__device__ __forceinline__ float block_sum256(float x, float* ws4, int t) {
    #pragma unroll
    for (int o = 1; o < 64; o <<= 1) x += __shfl_xor(x, o);
    if ((t & 63) == 0) ws4[t >> 6] = x;
    __syncthreads();
    float r = ws4[0] + ws4[1] + ws4[2] + ws4[3];
    __syncthreads();
    return r;
}

__global__ __launch_bounds__(256) void k_norm(float* __restrict__ P,
                                              float* __restrict__ sp) {
    int p = blockIdx.x;
    int c = threadIdx.x;
    __shared__ float ws4[4];
    float v = P[p * NCH + c];
    float mean = block_sum256(v, ws4, c) * (1.0f / 256.0f);
    float cen = v - mean;
    float n2 = block_sum256(cen * cen, ws4, c);
    float inv = 1.0f / fmaxf(sqrtf(n2), EPSN);
    float pn = cen * inv;
    P[p * NCH + c] = pn;
    float ssum = block_sum256(pn, ws4, c);
    if (c == 0) sp[p] = ssum;
}

// ---------------------------------------------------------------------------
// Kernel 2: dot products + per-group softmax partials.
// Thread <-> 1 pixel; block = 256 pixels; blockIdx.y = proto group (20 protos).
// Grid 64x16 = 1024 blocks = 4096 waves = 4 waves/SIMD.
// No LDS, no barriers. q loads lane-coalesced; PT/sp addresses wave-uniform
// (blockIdx.y + unrolled constants) -> scalar s_load + v_fmac_f32 v,s,v.
// q stats (mean/invnorm) computed redundantly per group, identical seq order.
// Emits per-(group,pixel) partial: (max, sumexp, sum d*exp, argmax) float4.
// ---------------------------------------------------------------------------
__global__ __launch_bounds__(256) void k_main(const float* __restrict__ qry,
                                              const float* __restrict__ P,
                                              const float* __restrict__ sp,
                                              float4* __restrict__ part) {
    int pix = blockIdx.x * 256 + threadIdx.x;
    int g = blockIdx.y;
    const float* prow = P + (size_t)g * PPG * NCH;

    float acc[PPG];
    #pragma unroll
    for (int j = 0; j < PPG; ++j) acc[j] = 0.f;
    float s1 = 0.f, s2 = 0.f;

    for (int cb = 0; cb < 16; ++cb) {
        float qv[16];
        #pragma unroll
        for (int i = 0; i < 16; ++i)
            qv[i] = qry[(size_t)(cb * 16 + i) * HW + pix];
        #pragma unroll
        for (int i = 0; i < 16; ++i) {
            s1 += qv[i];
            s2 = fmaf(qv[i], qv[i], s2);
        }
        #pragma unroll
        for (int j = 0; j < PPG; ++j) {
            const float* pr = prow + j * NCH + cb * 16;
            #pragma unroll
            for (int i = 0; i < 16; ++i)
                acc[j] = fmaf(qv[i], pr[i], acc[j]);
        }
    }

    float mean = s1 * (1.0f / 256.0f);
    float n2 = fmaxf(s2 - s1 * mean, 0.f);
    float invn = 1.0f / fmaxf(sqrtf(n2), EPSN);

    float m = -1e30f; int bj = 0;
    #pragma unroll
    for (int j = 0; j < PPG; ++j) {
        float d = TAU * invn * (acc[j] - mean * sp[g * PPG + j]);
        acc[j] = d;
        if (d > m) { m = d; bj = j; }
    }
    float S = 0.f, T = 0.f;
    #pragma unroll
    for (int j = 0; j < PPG; ++j) {
        float e = __expf(acc[j] - m);
        S += e; T += e * acc[j];
    }
    part[(size_t)g * HW + pix] = make_float4(m, S, T, (float)(g * PPG + bj));
}

// ---------------------------------------------------------------------------
// Kernel 3: merge 16 group-partials per pixel (online softmax merge, ascending
// group order -> first-occurrence argmax preserved), write both outputs.
// ---------------------------------------------------------------------------
__global__ __launch_bounds__(256) void k_merge(const float4* __restrict__ part,
                                               float* __restrict__ out) {
    int pix = blockIdx.x * 256 + threadIdx.x;
    float m = -1e30f, S = 0.f, T = 0.f, bm = -1e30f, bi = 0.f;
    #pragma unroll
    for (int g = 0; g < NGRP; ++g) {
        float4 v = part[(size_t)g * HW + pix];
        float nm = fmaxf(m, v.x);
        float wo = __expf(m - nm);
        float wn = __expf(v.x - nm);
        S = S * wo + v.y * wn;
        T = T * wo + v.z * wn;
        m = nm;
        if (v.x > bm) { bm = v.x; bi = v.w; }
    }
    out[pix] = T / S;            // pred_grid
    out[HW + pix] = bi;          // debug_assign
}

extern "C" void kernel_launch(void* const* d_in, const int* in_sizes, int n_in,
                              void* d_out, int out_size, void* d_ws, size_t ws_size,
                              hipStream_t stream) {
    const float* qry   = (const float*)d_in[0];   // (1,1,256,128,128)
    const float* sup_x = (const float*)d_in[1];   // (1,5,1,256,128,128)
    float* out = (float*)d_out;                   // 16384 pred + 16384 assign

    float*  P    = (float*)d_ws;                       // 320*256 fp32 (pooled -> normalized in place)
    float*  sp   = P + NPROT * NCH;                    // 320 fp32
    float4* part = (float4*)(sp + NPROT);              // 16*16384 float4 = 1 MB

    k_pool <<<5 * 256, 256, 0, stream>>>(sup_x, P);
    k_norm <<<NPROT, 256, 0, stream>>>(P, sp);
    k_main <<<dim3(HW / 256, NGRP), 256, 0, stream>>>(qry, P, sp, part);
    k_merge<<<HW / 256, 256, 0, stream>>>(part, out);
}

// Round 5
// 200.271 us; speedup vs baseline: 1.4966x; 1.2618x over previous
//
#include <hip/hip_runtime.h>

#define NCH   256
#define NPROT 320
#define HW    16384      // 128*128
#define TAU   20.0f
#define EPSN  1e-4f

// ---------------------------------------------------------------------------
// Kernel 1a: avg-pool sup_x (5,256,128,128) over 16x16 cells -> praw[p][c]
// One block per (s,c) plane. Fully coalesced float4 reads; no atomics.
// ---------------------------------------------------------------------------
__global__ __launch_bounds__(256) void k_pool(const float* __restrict__ sup_x,
                                              float* __restrict__ praw) {
    int b = blockIdx.x;            // s*256 + c
    int t = threadIdx.x;
    const float4* plane = (const float4*)(sup_x + (size_t)b * HW);
    float rsum[8];
    #pragma unroll
    for (int r = 0; r < 8; ++r) rsum[r] = 0.f;
    #pragma unroll
    for (int i = 0; i < 16; ++i) {
        float4 v = plane[i * 256 + t];          // h = i*8 + (t>>5), w4 = t&31
        rsum[i >> 1] += v.x + v.y + v.z + v.w;  // cell row R = h>>4 = i>>1
    }
    __shared__ float part[8][256];
    #pragma unroll
    for (int r = 0; r < 8; ++r) part[r][t] = rsum[r];
    __syncthreads();
    int R  = t >> 5;
    int cw = t & 31;               // = C*4 + bsub
    float s = 0.f;
    #pragma unroll
    for (int a = 0; a < 8; ++a) s += part[R][a * 32 + cw];
    s += __shfl_xor(s, 1);
    s += __shfl_xor(s, 2);
    if ((t & 3) == 0) {
        int shot = b >> 8, c = b & 255;
        int p = shot * 64 + R * 8 + (cw >> 2);
        praw[(size_t)p * NCH + c] = s * (1.0f / 256.0f);
    }
}

// ---------------------------------------------------------------------------
// Kernel 1b: per-proto center + safe-normalize; PT transposed (float4 per
// 4-channel block, proto-major within block); sp[p] = sum_c pro_n[p][c].
// ---------------------------------------------------------------------------
__device__ __forceinline__ float block_sum256(float x, float* ws4, int t) {
    #pragma unroll
    for (int o = 1; o < 64; o <<= 1) x += __shfl_xor(x, o);
    if ((t & 63) == 0) ws4[t >> 6] = x;
    __syncthreads();
    float r = ws4[0] + ws4[1] + ws4[2] + ws4[3];
    __syncthreads();
    return r;
}

__global__ __launch_bounds__(256) void k_norm(const float* __restrict__ praw,
                                              float* __restrict__ PT,
                                              float* __restrict__ sp) {
    int p = blockIdx.x;
    int c = threadIdx.x;
    __shared__ float ws4[4];
    float v = praw[p * NCH + c];
    float mean = block_sum256(v, ws4, c) * (1.0f / 256.0f);
    float cen = v - mean;
    float n2 = block_sum256(cen * cen, ws4, c);
    float inv = 1.0f / fmaxf(sqrtf(n2), EPSN);
    float pn = cen * inv;
    PT[(size_t)(c >> 2) * NPROT * 4 + p * 4 + (c & 3)] = pn;
    float ssum = block_sum256(pn, ws4, c);
    if (c == 0) sp[p] = ssum;
}

// ---------------------------------------------------------------------------
// Kernel 2: fused normalize(qry) -> 320 dots -> softmax-weighted mean + argmax
// 16 pixels/block, 256 threads = 4 waves -> grid 1024 = 4 blocks/CU
// (4 waves/SIMD). Wave w owns pixels w*4..w*4+3; lane l owns protos
// {l + 64j, j=0..4} (interleaved -> coalesced PT float4 loads). No explicit
// register pipelining (spills at the 64-VGPR allocation the compiler picks);
// TLP at 4 waves/SIMD hides the L2-resident PT load latency instead.
// ---------------------------------------------------------------------------
__global__ __launch_bounds__(256, 4) void k_main(const float* __restrict__ qry,
                                                 const float* __restrict__ PT,
                                                 const float* __restrict__ sp,
                                                 float* __restrict__ out) {
    // smem layout (floats):
    //  [0, 4160)      qlds 16 x 260  (later reused: M/S/T/I 4 x (16 x 65))
    //  [4160, 4416)   norm partial s1   (later reused: P2m/s/t/i 4 x 144)
    //  [4416, 4672)   norm partial s2
    //  [4736, 4752)   meanv ; [4752, 4768) invnv
    __shared__ __align__(16) float smem[4768];
    int t = threadIdx.x;
    int pixbase = blockIdx.x * 16;

    // ---- stage 16 pixels x 256 channels ----
    {
        int f4 = t & 3;            // float4-of-pixels (0..3)
        int c0 = t >> 2;           // 0..63
        #pragma unroll
        for (int i = 0; i < 4; ++i) {
            int c = c0 + 64 * i;
            float4 v = *(const float4*)(qry + (size_t)c * HW + pixbase + f4 * 4);
            int px = f4 * 4;
            smem[(px + 0) * 260 + c] = v.x;
            smem[(px + 1) * 260 + c] = v.y;
            smem[(px + 2) * 260 + c] = v.z;
            smem[(px + 3) * 260 + c] = v.w;
        }
    }
    __syncthreads();

    // ---- per-pixel mean and inverse safe-norm ----
    {
        int pix = t & 15, sub = t >> 4;     // 16 subs x 16 channels
        float s1 = 0.f, s2 = 0.f;
        #pragma unroll
        for (int j = 0; j < 16; ++j) {
            float q = smem[pix * 260 + sub * 16 + j];
            s1 += q; s2 += q * q;
        }
        smem[4160 + sub * 16 + pix] = s1;
        smem[4416 + sub * 16 + pix] = s2;
    }
    __syncthreads();
    if (t < 16) {
        float s1 = 0.f, s2 = 0.f;
        #pragma unroll
        for (int j = 0; j < 16; ++j) { s1 += smem[4160 + j * 16 + t]; s2 += smem[4416 + j * 16 + t]; }
        float mean = s1 * (1.0f / 256.0f);
        float n2 = fmaxf(s2 - s1 * mean, 0.f);
        smem[4736 + t] = mean;
        smem[4752 + t] = 1.0f / fmaxf(sqrtf(n2), EPSN);
    }
    __syncthreads();

    // ---- dot products: 4 pixels x 5 protos per thread ----
    int lane = t & 63;
    int w = t >> 6;
    float acc[4][5];
    #pragma unroll
    for (int i = 0; i < 4; ++i)
        #pragma unroll
        for (int j = 0; j < 5; ++j) acc[i][j] = 0.f;

    const float4* P4 = (const float4*)PT + lane;
    const float* qrow = smem + w * 4 * 260;

    #pragma unroll 2
    for (int cb = 0; cb < 64; ++cb) {
        const float4* Pn = P4 + (size_t)cb * NPROT;
        float4 pv[5];
        #pragma unroll
        for (int j = 0; j < 5; ++j) pv[j] = Pn[j * 64];
        #pragma unroll
        for (int i = 0; i < 4; ++i) {
            float4 qv = *(const float4*)(qrow + i * 260 + cb * 4);
            #pragma unroll
            for (int j = 0; j < 5; ++j) {
                acc[i][j] = fmaf(qv.x, pv[j].x, acc[i][j]);
                acc[i][j] = fmaf(qv.y, pv[j].y, acc[i][j]);
                acc[i][j] = fmaf(qv.z, pv[j].z, acc[i][j]);
                acc[i][j] = fmaf(qv.w, pv[j].w, acc[i][j]);
            }
        }
    }

    // ---- per-thread softmax partials over 5 protos, per pixel ----
    float spv[5];
    #pragma unroll
    for (int j = 0; j < 5; ++j) spv[j] = sp[lane + 64 * j];

    float m4[4], S4[4], T4[4], I4[4];
    #pragma unroll
    for (int i = 0; i < 4; ++i) {
        int pix = w * 4 + i;
        float mean = smem[4736 + pix], invn = smem[4752 + pix];
        float d[5];
        float m = -1e30f; int bj = 0;
        #pragma unroll
        for (int j = 0; j < 5; ++j) {
            d[j] = TAU * invn * (acc[i][j] - mean * spv[j]);
            if (d[j] > m) { m = d[j]; bj = j; }
        }
        float S = 0.f, T = 0.f;
        #pragma unroll
        for (int j = 0; j < 5; ++j) {
            float e = __expf(d[j] - m);
            S += e; T += e * d[j];
        }
        m4[i] = m; S4[i] = S; T4[i] = T; I4[i] = (float)(lane + 64 * bj);
    }
    __syncthreads();   // all waves done reading qlds; safe to alias

    float* M  = smem;
    float* Sa = smem + 1040;
    float* Ta = smem + 2080;
    float* Ia = smem + 3120;
    #pragma unroll
    for (int i = 0; i < 4; ++i) {
        int pix = w * 4 + i;
        M [pix * 65 + lane] = m4[i];
        Sa[pix * 65 + lane] = S4[i];
        Ta[pix * 65 + lane] = T4[i];
        Ia[pix * 65 + lane] = I4[i];
    }
    __syncthreads();

    // ---- stage 2: merge 8 lanes per (pixel, octant) ----
    float* P2m = smem + 4160;
    float* P2s = smem + 4304;
    float* P2t = smem + 4448;
    float* P2i = smem + 4592;
    if (t < 128) {
        int pix = t >> 3, oct = t & 7;
        int base = pix * 65 + oct * 8;
        float gm = -1e30f;
        #pragma unroll
        for (int k = 0; k < 8; ++k) gm = fmaxf(gm, M[base + k]);
        float S = 0.f, T = 0.f, bi = 0.f, bm = -1e30f;
        #pragma unroll
        for (int k = 0; k < 8; ++k) {
            float mk = M[base + k];
            float wg = __expf(mk - gm);
            S += Sa[base + k] * wg;
            T += Ta[base + k] * wg;
            if (mk > bm) { bm = mk; bi = Ia[base + k]; }
        }
        P2m[pix * 9 + oct] = gm;
        P2s[pix * 9 + oct] = S;
        P2t[pix * 9 + oct] = T;
        P2i[pix * 9 + oct] = bi;
    }
    __syncthreads();

    // ---- stage 3: merge 8 octants, write out ----
    if (t < 16) {
        float gm = -1e30f;
        #pragma unroll
        for (int k = 0; k < 8; ++k) gm = fmaxf(gm, P2m[t * 9 + k]);
        float S = 0.f, T = 0.f, bi = 0.f, bm = -1e30f;
        #pragma unroll
        for (int k = 0; k < 8; ++k) {
            float mk = P2m[t * 9 + k];
            float wg = __expf(mk - gm);
            S += P2s[t * 9 + k] * wg;
            T += P2t[t * 9 + k] * wg;
            if (mk > bm) { bm = mk; bi = P2i[t * 9 + k]; }
        }
        out[pixbase + t] = T / S;           // pred_grid
        out[HW + pixbase + t] = bi;         // debug_assign
    }
}

extern "C" void kernel_launch(void* const* d_in, const int* in_sizes, int n_in,
                              void* d_out, int out_size, void* d_ws, size_t ws_size,
                              hipStream_t stream) {
    const float* qry   = (const float*)d_in[0];   // (1,1,256,128,128)
    const float* sup_x = (const float*)d_in[1];   // (1,5,1,256,128,128)
    float* out = (float*)d_out;                   // 16384 pred + 16384 assign

    float* praw = (float*)d_ws;                          // 320*256 fp32
    float* PT   = praw + NPROT * NCH;                    // 320*256 fp32 (transposed)
    float* sp   = PT + NPROT * NCH;                      // 320 fp32

    k_pool<<<5 * 256, 256, 0, stream>>>(sup_x, praw);
    k_norm<<<NPROT, 256, 0, stream>>>(praw, PT, sp);
    k_main<<<HW / 16, 256, 0, stream>>>(qry, PT, sp, out);
}